// Round 5
// baseline (1115.045 us; speedup 1.0000x reference)
//
#include <hip/hip_runtime.h>

typedef short sh8 __attribute__((ext_vector_type(8)));
typedef __bf16 bf8 __attribute__((ext_vector_type(8)));
typedef float f4 __attribute__((ext_vector_type(4)));
typedef unsigned int u4 __attribute__((ext_vector_type(4)));

#define DEV __device__ __forceinline__

DEV unsigned int fbits(float f){ union{float f;unsigned int u;}v; v.f=f; return v.u; }
DEV float bitsf(unsigned int u){ union{unsigned int u;float f;}v; v.u=u; return v.f; }
DEV float bf2f(unsigned short u) { return bitsf(((unsigned int)u) << 16); }
// RTNE f32->bf16 (proven numerics from rounds 2/4 — DO NOT CHANGE)
DEV unsigned short f2bf(float f) {
    unsigned int x = fbits(f);
    return (unsigned short)((x + 0x7fffu + ((x >> 16) & 1u)) >> 16);
}
// jax.nn.softplus(x) = max(x,0) + log1p(exp(-|x|)) in f32 (proven rounds 2/4)
DEV float sp_f(float x) {
    return fmaxf(x, 0.0f) + log1pf(expf(-fabsf(x)));
}

#define MFMA(a, b, c) __builtin_amdgcn_mfma_f32_16x16x32_bf16(__builtin_bit_cast(bf8, a), __builtin_bit_cast(bf8, b), c, 0, 0, 0)

// ---------------- T = einsum(w_mean_norm, bone_transforms) ----------------
__global__ void t_kernel(const float* __restrict__ sw,
                         const float* __restrict__ bt,
                         float* __restrict__ Tout, int V) {
    __shared__ float red[4 * 24];
    __shared__ float mm[24];
    float p[24];
#pragma unroll
    for (int j = 0; j < 24; j++) p[j] = 0.0f;
    for (int v = threadIdx.x; v < V; v += 256) {
        const float* row = sw + v * 24;
#pragma unroll
        for (int c4 = 0; c4 < 6; c4++) {
            f4 a = *(const f4*)(row + c4 * 4);
#pragma unroll
            for (int e = 0; e < 4; e++) p[c4 * 4 + e] += a[e];
        }
    }
#pragma unroll
    for (int j = 0; j < 24; j++) {
#pragma unroll
        for (int msk = 1; msk < 64; msk <<= 1) p[j] += __shfl_xor(p[j], msk);
    }
    int lane = threadIdx.x & 63, wid = threadIdx.x >> 6;
    if (lane == 0) {
#pragma unroll
        for (int j = 0; j < 24; j++) red[wid * 24 + j] = p[j];
    }
    __syncthreads();
    if (threadIdx.x < 24) {
        float s = red[threadIdx.x] + red[24 + threadIdx.x] + red[48 + threadIdx.x] + red[72 + threadIdx.x];
        mm[threadIdx.x] = s / (float)V;
    }
    __syncthreads();
    if (threadIdx.x < 16) {
        float tot = 0.0f;
#pragma unroll
        for (int j = 0; j < 24; j++) tot += mm[j];
        float a = 0.0f;
#pragma unroll
        for (int j = 0; j < 24; j++) a += (mm[j] / tot) * bt[j * 16 + threadIdx.x];
        Tout[threadIdx.x] = a;
    }
}

// ---------------- main: trace + secant + sample ----------------
// wave = 16 rays; lane l: ray m = l&15, k-slice u = l>>4
// W2^T as 3 RTNE-split bf16 copies in FRAGMENT-CONTIGUOUS LDS:
//   frag f=(nt*4+ks): lane l holds B[k=ks*32+(l>>4)*8+j][n=nt*16+(l&15)], j=0..7
//   u16 offset = split*16384 + f*512 + l*8 + j  -> ds_read_b128 conflict-free
// ALL B-splits read from LDS (no register residency) to stay under the 256
// arch-VGPR cap with zero scratch spill.
__global__ __launch_bounds__(256, 1) void main_kernel(
    const float* __restrict__ cam_loc, const float* __restrict__ dirs,
    const float* __restrict__ bbi,     const float* __restrict__ loc,
    const float* __restrict__ scf,     const float* __restrict__ trans,
    const float* __restrict__ cmin,    const float* __restrict__ cmax,
    const float* __restrict__ cent,    const float* __restrict__ W1,
    const float* __restrict__ b1,      const float* __restrict__ W2,
    const float* __restrict__ b2,      const float* __restrict__ W3,
    const float* __restrict__ b3,      const float* __restrict__ Tmat,
    float* __restrict__ out, int N) {

    __shared__ unsigned short wfrag[3 * 16384];   // 96 KB
    __shared__ f4 w1p[16 * 9];                    // stride-9 pad
    __shared__ float b2s[128], w3s[128];

    const int tid = threadIdx.x;

    // ---- stage W2 (f32) -> 3 RTNE splits, fragment order ----
    for (int i4 = tid; i4 < 4096; i4 += 256) {
        f4 v = *(const f4*)(W2 + i4 * 4);
        int k = (i4 * 4) >> 7;          // same k for all 4 elems (128 % 4 == 0)
        int n0 = (i4 * 4) & 127;
        int lanehalf = ((k >> 3) & 3) << 4;
        int fk = k >> 5;
        int j = k & 7;
#pragma unroll
        for (int e = 0; e < 4; e++) {
            int n = n0 + e;
            float w = v[e];
            unsigned short u0 = f2bf(w);   float g0 = bf2f(u0);
            float r1 = w - g0;             unsigned short u1 = f2bf(r1); float g1 = bf2f(u1);
            float r2 = r1 - g1;            unsigned short u2 = f2bf(r2);
            int off = ((n >> 4) * 4 + fk) * 512 + (lanehalf | (n & 15)) * 8 + j;
            wfrag[off]         = u0;
            wfrag[16384 + off] = u1;
            wfrag[32768 + off] = u2;
        }
    }
    if (tid < 128) {
        int k = tid, ks = k >> 5, uu = (k >> 3) & 3, j = k & 7;
        f4 w;
        w.x = W1[k]; w.y = W1[128 + k]; w.z = W1[256 + k]; w.w = b1[k];
        w1p[(ks * 4 + uu) * 9 + j] = w;
        b2s[k] = b2[k];
        w3s[k] = W3[k];
    }
    __syncthreads();   // last block-wide sync

    const int lane = tid & 63;
    const int wv = tid >> 6;
    const int m = lane & 15, u = lane >> 4;
    const int rayBase = (blockIdx.x * 4 + wv) * 16;
    const int R = rayBase + m;

    const int O1 = 3 * N, O2 = 4 * N, O3 = 5 * N, O4 = 101 * N, O5 = 133 * N, O6 = 645 * N;

    float camx = cam_loc[0], camy = cam_loc[1], camz = cam_loc[2];
    float A[3], Bc[3];
#pragma unroll
    for (int c = 0; c < 3; c++) {
        float he = 0.5f * (cmax[c] - cmin[c]);
        float sc = scf[c];
        float off = (0.0f - trans[c] - loc[c]) * sc - cent[c];
        A[c] = sc / he; Bc[c] = off / he;
    }
    float dx = dirs[R * 3 + 0], dy = dirs[R * 3 + 1], dz = dirs[R * 3 + 2];
    float nearv = bbi[R * 2 + 0], farv = bbi[R * 2 + 1];

    float w3v[8], b2v[8];
#pragma unroll
    for (int nt = 0; nt < 8; nt++) { w3v[nt] = w3s[nt * 16 + m]; b2v[nt] = b2s[nt * 16 + m]; }
    float b3v = b3[0];

    // ---- one SDF eval at t; returns s and xn ----
    auto EVAL = [&](float t, float& sout, float& x0o, float& x1o, float& x2o) {
        float y0 = fmaf(t, dx, camx), y1 = fmaf(t, dy, camy), y2 = fmaf(t, dz, camz);
        float x0 = fmaf(y0, A[0], Bc[0]), x1 = fmaf(y1, A[1], Bc[1]), x2 = fmaf(y2, A[2], Bc[2]);
        // A-fragments: RTNE triple-split, packed into words (lo=even j, hi=odd j)
        u4 a0w[4], a1w[4], a2w[4];
#pragma unroll
        for (int ks = 0; ks < 4; ks++) {
#pragma unroll
            for (int jp = 0; jp < 4; jp++) {
                f4 wA = w1p[(ks * 4 + u) * 9 + 2 * jp];
                f4 wB = w1p[(ks * 4 + u) * 9 + 2 * jp + 1];
                float hA = fmaf(x0, wA.x, fmaf(x1, wA.y, fmaf(x2, wA.z, wA.w)));
                float hB = fmaf(x0, wB.x, fmaf(x1, wB.y, fmaf(x2, wB.z, wB.w)));
                float sA = sp_f(hA), sB = sp_f(hB);
                unsigned short A0 = f2bf(sA); float fA0 = bf2f(A0);
                unsigned short B0 = f2bf(sB); float fB0 = bf2f(B0);
                float rA1 = sA - fA0, rB1 = sB - fB0;
                unsigned short A1 = f2bf(rA1); float fA1 = bf2f(A1);
                unsigned short B1 = f2bf(rB1); float fB1 = bf2f(B1);
                float rA2 = rA1 - fA1, rB2 = rB1 - fB1;
                unsigned short A2 = f2bf(rA2);
                unsigned short B2 = f2bf(rB2);
                a0w[ks][jp] = (unsigned int)A0 | ((unsigned int)B0 << 16);
                a1w[ks][jp] = (unsigned int)A1 | ((unsigned int)B1 << 16);
                a2w[ks][jp] = (unsigned int)A2 | ((unsigned int)B2 << 16);
            }
        }
        float pr0 = 0.f, pr1 = 0.f, pr2 = 0.f, pr3 = 0.f;
#pragma unroll
        for (int g = 0; g < 2; g++) {
            f4 c[4];
#pragma unroll
            for (int q = 0; q < 4; q++) {
                float b = b2v[g * 4 + q];
                c[q] = (f4){b, b, b, b};
            }
            // passes 1-3: split0 of B from LDS (a0*b0, a1*b0, a2*b0)
#pragma unroll
            for (int ks = 0; ks < 4; ks++) {
                sh8 t0 = *(const sh8*)&wfrag[((g * 4 + 0) * 4 + ks) * 512 + lane * 8];
                sh8 t1 = *(const sh8*)&wfrag[((g * 4 + 1) * 4 + ks) * 512 + lane * 8];
                sh8 t2 = *(const sh8*)&wfrag[((g * 4 + 2) * 4 + ks) * 512 + lane * 8];
                sh8 t3 = *(const sh8*)&wfrag[((g * 4 + 3) * 4 + ks) * 512 + lane * 8];
                c[0] = MFMA(a0w[ks], t0, c[0]); c[1] = MFMA(a0w[ks], t1, c[1]);
                c[2] = MFMA(a0w[ks], t2, c[2]); c[3] = MFMA(a0w[ks], t3, c[3]);
            }
#pragma unroll
            for (int ks = 0; ks < 4; ks++) {
                sh8 t0 = *(const sh8*)&wfrag[((g * 4 + 0) * 4 + ks) * 512 + lane * 8];
                sh8 t1 = *(const sh8*)&wfrag[((g * 4 + 1) * 4 + ks) * 512 + lane * 8];
                sh8 t2 = *(const sh8*)&wfrag[((g * 4 + 2) * 4 + ks) * 512 + lane * 8];
                sh8 t3 = *(const sh8*)&wfrag[((g * 4 + 3) * 4 + ks) * 512 + lane * 8];
                c[0] = MFMA(a1w[ks], t0, c[0]); c[1] = MFMA(a1w[ks], t1, c[1]);
                c[2] = MFMA(a1w[ks], t2, c[2]); c[3] = MFMA(a1w[ks], t3, c[3]);
            }
#pragma unroll
            for (int ks = 0; ks < 4; ks++) {
                sh8 t0 = *(const sh8*)&wfrag[((g * 4 + 0) * 4 + ks) * 512 + lane * 8];
                sh8 t1 = *(const sh8*)&wfrag[((g * 4 + 1) * 4 + ks) * 512 + lane * 8];
                sh8 t2 = *(const sh8*)&wfrag[((g * 4 + 2) * 4 + ks) * 512 + lane * 8];
                sh8 t3 = *(const sh8*)&wfrag[((g * 4 + 3) * 4 + ks) * 512 + lane * 8];
                c[0] = MFMA(a2w[ks], t0, c[0]); c[1] = MFMA(a2w[ks], t1, c[1]);
                c[2] = MFMA(a2w[ks], t2, c[2]); c[3] = MFMA(a2w[ks], t3, c[3]);
            }
            // passes 4-5: split1 from LDS (a0*b1, a1*b1)
#pragma unroll
            for (int ks = 0; ks < 4; ks++) {
                sh8 t0 = *(const sh8*)&wfrag[16384 + ((g * 4 + 0) * 4 + ks) * 512 + lane * 8];
                sh8 t1 = *(const sh8*)&wfrag[16384 + ((g * 4 + 1) * 4 + ks) * 512 + lane * 8];
                sh8 t2 = *(const sh8*)&wfrag[16384 + ((g * 4 + 2) * 4 + ks) * 512 + lane * 8];
                sh8 t3 = *(const sh8*)&wfrag[16384 + ((g * 4 + 3) * 4 + ks) * 512 + lane * 8];
                c[0] = MFMA(a0w[ks], t0, c[0]); c[1] = MFMA(a0w[ks], t1, c[1]);
                c[2] = MFMA(a0w[ks], t2, c[2]); c[3] = MFMA(a0w[ks], t3, c[3]);
                c[0] = MFMA(a1w[ks], t0, c[0]); c[1] = MFMA(a1w[ks], t1, c[1]);
                c[2] = MFMA(a1w[ks], t2, c[2]); c[3] = MFMA(a1w[ks], t3, c[3]);
            }
            // pass 6: split2 from LDS (a0*b2)
#pragma unroll
            for (int ks = 0; ks < 4; ks++) {
                sh8 t0 = *(const sh8*)&wfrag[32768 + ((g * 4 + 0) * 4 + ks) * 512 + lane * 8];
                sh8 t1 = *(const sh8*)&wfrag[32768 + ((g * 4 + 1) * 4 + ks) * 512 + lane * 8];
                sh8 t2 = *(const sh8*)&wfrag[32768 + ((g * 4 + 2) * 4 + ks) * 512 + lane * 8];
                sh8 t3 = *(const sh8*)&wfrag[32768 + ((g * 4 + 3) * 4 + ks) * 512 + lane * 8];
                c[0] = MFMA(a0w[ks], t0, c[0]); c[1] = MFMA(a0w[ks], t1, c[1]);
                c[2] = MFMA(a0w[ks], t2, c[2]); c[3] = MFMA(a0w[ks], t3, c[3]);
            }
            // epilogue: softplus + W3 dot (component r = ray u*4+r, col n=nt*16+m)
#pragma unroll
            for (int q = 0; q < 4; q++) {
                float wv3 = w3v[g * 4 + q];
                pr0 = fmaf(sp_f(c[q].x), wv3, pr0);
                pr1 = fmaf(sp_f(c[q].y), wv3, pr1);
                pr2 = fmaf(sp_f(c[q].z), wv3, pr2);
                pr3 = fmaf(sp_f(c[q].w), wv3, pr3);
            }
        }
        // reduce over the 16 m-lanes (n-dimension)
#pragma unroll
        for (int msk = 1; msk < 16; msk <<= 1) {
            pr0 += __shfl_xor(pr0, msk); pr1 += __shfl_xor(pr1, msk);
            pr2 += __shfl_xor(pr2, msk); pr3 += __shfl_xor(pr3, msk);
        }
        pr0 += b3v; pr1 += b3v; pr2 += b3v; pr3 += b3v;
        // redistribute: ray m lives at lane (m>>2)<<4, component m&3
        int srcl = (m >> 2) << 4;
        float q0 = __shfl(pr0, srcl), q1 = __shfl(pr1, srcl);
        float q2 = __shfl(pr2, srcl), q3 = __shfl(pr3, srcl);
        float sa = (m & 1) ? q1 : q0, sb = (m & 1) ? q3 : q2;
        sout = (m & 2) ? sb : sa;
        x0o = x0; x1o = x1; x2o = x2;
    };

    // ---- sphere tracing ----
    float acc = nearv;
    bool unf = nearv < farv;
    bool dv = !unf;
    float sv, xv0 = 0.f, xv1 = 0.f, xv2 = 0.f;
#pragma unroll 1
    for (int it = 0; it < 32; ++it) {
        if (!__any((int)unf)) break;
        EVAL(acc, sv, xv0, xv1, xv2);
        float smv = fminf(fmaxf(sv, -0.1f), 0.1f);
        bool convu = unf;
        bool upd = unf && (fabsf(smv) > 1e-5f) && (fabsf(sv) < 1000000.0f);
        if (upd) acc = acc + smv;
        dv = upd ? (acc >= farv) : dv;
        bool remove = (convu && (fabsf(sv) <= 1e-5f)) || dv;
        unf = unf && !remove;
    }

    // ---- secant (last iteration is the final eval) ----
    float t0 = fminf(fmaxf(acc - 0.1f, nearv), farv);
    float t1 = fminf(fmaxf(acc, nearv), farv);
    float f0;
    EVAL(t0, f0, xv0, xv1, xv2);
    float f1 = 0.0f;
#pragma unroll 1
    for (int si = 0; si < 9; ++si) {
        float f1s;
        EVAL(t1, f1s, xv0, xv1, xv2);
        if (si == 8) { f1 = f1s; break; }
        float den = f0 - f1s;
        den = (fabsf(den) < 1e-9f) ? 1e-9f : den;
        float t2 = t1 - f1s * (t1 - t0) / den;
        t2 = fminf(fmaxf(t2, nearv), farv);
        t0 = t1; f0 = f1s; t1 = t2;
    }
    bool conv = (fabsf(f1) <= 1e-5f) && (t1 >= nearv) && (t1 <= farv);

    if (u == 0) {
        out[R * 3 + 0] = xv0;
        out[R * 3 + 1] = xv1;
        out[R * 3 + 2] = xv2;
        out[O1 + R] = conv ? 1.0f : 0.0f;
        out[O2 + R] = conv ? t1 : nearv;
        out[O6 + R] = conv ? 1.0f : 0.0f;
    }

    // ---- z samples: merge(sorted z_near, sorted z_far) if conv, else uniform ----
    float zreg[8];
    if (conv) {
        float a0v = t1 - 0.05f, sa = 0.1f / 15.0f;
        float b0v = nearv, sb = (farv - nearv) / 15.0f;
        int ia = 0, ib = 0;
#pragma unroll
        for (int i = 0; i < 32; i++) {
            float va = fmaf((float)ia, sa, a0v);
            float vb = fmaf((float)ib, sb, b0v);
            bool ta = (ia < 16) && ((ib >= 16) || (va <= vb));
            float zv = ta ? va : vb;
            if (ta) ia++; else ib++;
            if ((i >> 3) == u) zreg[i & 7] = zv;
        }
    } else {
        float rng = farv - nearv;
#pragma unroll
        for (int q = 0; q < 8; q++) {
            int i = u * 8 + q;
            zreg[q] = fmaf((float)i * (1.0f / 31.0f), rng, nearv);
        }
    }

    // dists
    {
        f4 d0, d1;
#pragma unroll
        for (int q = 0; q < 4; q++) { d0[q] = zreg[q]; d1[q] = zreg[4 + q]; }
        *(f4*)&out[O4 + R * 32 + u * 8] = d0;
        *(f4*)&out[O4 + R * 32 + u * 8 + 4] = d1;
    }

    // points
    {
        f4 pk[6];
#pragma unroll
        for (int q = 0; q < 8; q++) {
            float z = zreg[q];
            float y0 = fmaf(z, dx, camx), y1 = fmaf(z, dy, camy), y2 = fmaf(z, dz, camz);
            float v0 = fmaf(y0, A[0], Bc[0]);
            float v1 = fmaf(y1, A[1], Bc[1]);
            float v2 = fmaf(y2, A[2], Bc[2]);
#pragma unroll
            for (int c = 0; c < 3; c++) {
                int ee = q * 3 + c;
                float vv = (c == 0) ? v0 : ((c == 1) ? v1 : v2);
                pk[ee >> 2][ee & 3] = vv;
            }
        }
        int pbase = O3 + R * 96 + u * 24;
#pragma unroll
        for (int s6 = 0; s6 < 6; s6++) *(f4*)&out[pbase + s6 * 4] = pk[s6];
    }

    // ---- sampler_transforms: broadcast T rows, coalesced per wave ----
    {
        f4 myrow = *(const f4*)&Tmat[(lane & 3) * 4];
        int base = O5 + rayBase * 512;
#pragma unroll
        for (int cc = 0; cc < 32; cc++) {
            int g = lane + 64 * cc;
            *(f4*)&out[base + g * 4] = myrow;
        }
    }
}

extern "C" void kernel_launch(void* const* d_in, const int* in_sizes, int n_in,
                              void* d_out, int out_size, void* d_ws, size_t ws_size,
                              hipStream_t stream) {
    (void)n_in; (void)out_size; (void)ws_size;
    const float* cam  = (const float*)d_in[0];
    const float* dirs = (const float*)d_in[1];
    const float* bbi  = (const float*)d_in[2];
    const float* loc  = (const float*)d_in[3];
    const float* scf  = (const float*)d_in[4];
    const float* sw   = (const float*)d_in[7];
    const float* bt   = (const float*)d_in[8];
    const float* trn  = (const float*)d_in[9];
    const float* cmn  = (const float*)d_in[10];
    const float* cmx  = (const float*)d_in[11];
    const float* cen  = (const float*)d_in[12];
    const float* W1   = (const float*)d_in[13];
    const float* b1   = (const float*)d_in[14];
    const float* W2   = (const float*)d_in[15];
    const float* b2   = (const float*)d_in[16];
    const float* W3   = (const float*)d_in[17];
    const float* b3   = (const float*)d_in[18];

    float* Tout = (float*)d_ws;
    int N = in_sizes[1] / 3;
    int V = in_sizes[7] / 24;

    hipLaunchKernelGGL(t_kernel, dim3(1), dim3(256), 0, stream, sw, bt, Tout, V);
    hipLaunchKernelGGL(main_kernel, dim3(N / 64), dim3(256), 0, stream,
                       cam, dirs, bbi, loc, scf, trn, cmn, cmx, cen,
                       W1, b1, W2, b2, W3, b3, Tout,
                       (float*)d_out, N);
}

// Round 6
// 919.129 us; speedup vs baseline: 1.2132x; 1.2132x over previous
//
#include <hip/hip_runtime.h>

typedef short sh8 __attribute__((ext_vector_type(8)));
typedef __bf16 bf8 __attribute__((ext_vector_type(8)));
typedef float f4 __attribute__((ext_vector_type(4)));
typedef unsigned int u4 __attribute__((ext_vector_type(4)));

#define DEV __device__ __forceinline__

DEV unsigned int fbits(float f){ union{float f;unsigned int u;}v; v.f=f; return v.u; }
DEV float bitsf(unsigned int u){ union{unsigned int u;float f;}v; v.u=u; return v.f; }
DEV float bf2f(unsigned short u) { return bitsf(((unsigned int)u) << 16); }
// RTNE f32->bf16 (proven numerics rounds 2/4/5 — DO NOT CHANGE)
DEV unsigned short f2bf(float f) {
    unsigned int x = fbits(f);
    return (unsigned short)((x + 0x7fffu + ((x >> 16) & 1u)) >> 16);
}
// jax.nn.softplus(x) = max(x,0) + log1p(exp(-|x|)) in f32 (proven — DO NOT CHANGE)
DEV float sp_f(float x) {
    return fmaxf(x, 0.0f) + log1pf(expf(-fabsf(x)));
}

#define MFMA(a, b, c) __builtin_amdgcn_mfma_f32_16x16x32_bf16(__builtin_bit_cast(bf8, a), __builtin_bit_cast(bf8, b), c, 0, 0, 0)

// ---------------- T = einsum(w_mean_norm, bone_transforms) ----------------
__global__ void t_kernel(const float* __restrict__ sw,
                         const float* __restrict__ bt,
                         float* __restrict__ Tout, int V) {
    __shared__ float red[4 * 24];
    __shared__ float mm[24];
    float p[24];
#pragma unroll
    for (int j = 0; j < 24; j++) p[j] = 0.0f;
    for (int v = threadIdx.x; v < V; v += 256) {
        const float* row = sw + v * 24;
#pragma unroll
        for (int c4 = 0; c4 < 6; c4++) {
            f4 a = *(const f4*)(row + c4 * 4);
#pragma unroll
            for (int e = 0; e < 4; e++) p[c4 * 4 + e] += a[e];
        }
    }
#pragma unroll
    for (int j = 0; j < 24; j++) {
#pragma unroll
        for (int msk = 1; msk < 64; msk <<= 1) p[j] += __shfl_xor(p[j], msk);
    }
    int lane = threadIdx.x & 63, wid = threadIdx.x >> 6;
    if (lane == 0) {
#pragma unroll
        for (int j = 0; j < 24; j++) red[wid * 24 + j] = p[j];
    }
    __syncthreads();
    if (threadIdx.x < 24) {
        float s = red[threadIdx.x] + red[24 + threadIdx.x] + red[48 + threadIdx.x] + red[72 + threadIdx.x];
        mm[threadIdx.x] = s / (float)V;
    }
    __syncthreads();
    if (threadIdx.x < 16) {
        float tot = 0.0f;
#pragma unroll
        for (int j = 0; j < 24; j++) tot += mm[j];
        float a = 0.0f;
#pragma unroll
        for (int j = 0; j < 24; j++) a += (mm[j] / tot) * bt[j * 16 + threadIdx.x];
        Tout[threadIdx.x] = a;
    }
}

// ---------------- main: trace + secant + sample ----------------
// wave = 16 rays; lane l: ray m = l&15, k-slice u = l>>4
// W2^T as 3 RTNE-split bf16 copies in FRAGMENT-CONTIGUOUS LDS:
//   frag fi=(nt*4+ks): lane l holds B[k=ks*32+(l>>4)*8+j][n=nt*16+(l&15)], j=0..7
//   u16 offset = split*16384 + fi*512 + l*8 + j  -> ds_read_b128 conflict-free
// EVAL is ks-outer: A-split words for one k-slice produced just-in-time and
// consumed immediately -> minimal live set, no scratch spill.
__global__ __launch_bounds__(256, 1) void main_kernel(
    const float* __restrict__ cam_loc, const float* __restrict__ dirs,
    const float* __restrict__ bbi,     const float* __restrict__ loc,
    const float* __restrict__ scf,     const float* __restrict__ trans,
    const float* __restrict__ cmin,    const float* __restrict__ cmax,
    const float* __restrict__ cent,    const float* __restrict__ W1,
    const float* __restrict__ b1,      const float* __restrict__ W2,
    const float* __restrict__ b2,      const float* __restrict__ W3,
    const float* __restrict__ b3,      const float* __restrict__ Tmat,
    float* __restrict__ out, int N) {

    __shared__ unsigned short wfrag[3 * 16384];   // 96 KB
    __shared__ f4 w1p[16 * 9];                    // stride-9 pad
    __shared__ float b2s[128], w3s[128];

    const int tid = threadIdx.x;

    // ---- stage W2 (f32) -> 3 RTNE splits, fragment order (bit-exact) ----
    for (int i4 = tid; i4 < 4096; i4 += 256) {
        f4 v = *(const f4*)(W2 + i4 * 4);
        int k = (i4 * 4) >> 7;          // same k for all 4 elems (128 % 4 == 0)
        int n0 = (i4 * 4) & 127;
        int lanehalf = ((k >> 3) & 3) << 4;
        int fk = k >> 5;
        int j = k & 7;
#pragma unroll
        for (int e = 0; e < 4; e++) {
            int n = n0 + e;
            float w = v[e];
            unsigned short u0 = f2bf(w);   float g0 = bf2f(u0);
            float r1 = w - g0;             unsigned short u1 = f2bf(r1); float g1 = bf2f(u1);
            float r2 = r1 - g1;            unsigned short u2 = f2bf(r2);
            int off = ((n >> 4) * 4 + fk) * 512 + (lanehalf | (n & 15)) * 8 + j;
            wfrag[off]         = u0;
            wfrag[16384 + off] = u1;
            wfrag[32768 + off] = u2;
        }
    }
    if (tid < 128) {
        int k = tid, ks = k >> 5, uu = (k >> 3) & 3, j = k & 7;
        f4 w;
        w.x = W1[k]; w.y = W1[128 + k]; w.z = W1[256 + k]; w.w = b1[k];
        w1p[(ks * 4 + uu) * 9 + j] = w;
        b2s[k] = b2[k];
        w3s[k] = W3[k];
    }
    __syncthreads();   // last block-wide sync

    const int lane = tid & 63;
    const int wv = tid >> 6;
    const int m = lane & 15, u = lane >> 4;
    const int rayBase = (blockIdx.x * 4 + wv) * 16;
    const int R = rayBase + m;

    const int O1 = 3 * N, O2 = 4 * N, O3 = 5 * N, O4 = 101 * N, O5 = 133 * N, O6 = 645 * N;

    float camx = cam_loc[0], camy = cam_loc[1], camz = cam_loc[2];
    float A[3], Bc[3];
#pragma unroll
    for (int c = 0; c < 3; c++) {
        float he = 0.5f * (cmax[c] - cmin[c]);
        float sc = scf[c];
        float off = (0.0f - trans[c] - loc[c]) * sc - cent[c];
        A[c] = sc / he; Bc[c] = off / he;
    }
    float dx = dirs[R * 3 + 0], dy = dirs[R * 3 + 1], dz = dirs[R * 3 + 2];
    float nearv = bbi[R * 2 + 0], farv = bbi[R * 2 + 1];

    float w3v[8], b2v[8];
#pragma unroll
    for (int nt = 0; nt < 8; nt++) { w3v[nt] = w3s[nt * 16 + m]; b2v[nt] = b2s[nt * 16 + m]; }
    float b3v = b3[0];

    // ---- one SDF eval at t; returns s only ----
    auto EVAL = [&](float t, float& sout) {
        float y0 = fmaf(t, dx, camx), y1 = fmaf(t, dy, camy), y2 = fmaf(t, dz, camz);
        float x0 = fmaf(y0, A[0], Bc[0]), x1 = fmaf(y1, A[1], Bc[1]), x2 = fmaf(y2, A[2], Bc[2]);
        f4 c[8];
#pragma unroll
        for (int f = 0; f < 8; f++) {
            float b = b2v[f];
            c[f] = (f4){b, b, b, b};
        }
#pragma unroll
        for (int ks = 0; ks < 4; ks++) {
            // A-split words for this k-slice (8 neurons -> 4 words per split)
            u4 a0w, a1w, a2w;
#pragma unroll
            for (int jp = 0; jp < 4; jp++) {
                f4 wA = w1p[(ks * 4 + u) * 9 + 2 * jp];
                f4 wB = w1p[(ks * 4 + u) * 9 + 2 * jp + 1];
                float hA = fmaf(x0, wA.x, fmaf(x1, wA.y, fmaf(x2, wA.z, wA.w)));
                float hB = fmaf(x0, wB.x, fmaf(x1, wB.y, fmaf(x2, wB.z, wB.w)));
                float sA = sp_f(hA), sB = sp_f(hB);
                unsigned short A0 = f2bf(sA); float fA0 = bf2f(A0);
                unsigned short B0 = f2bf(sB); float fB0 = bf2f(B0);
                float rA1 = sA - fA0, rB1 = sB - fB0;
                unsigned short A1 = f2bf(rA1); float fA1 = bf2f(A1);
                unsigned short B1 = f2bf(rB1); float fB1 = bf2f(B1);
                float rA2 = rA1 - fA1, rB2 = rB1 - fB1;
                unsigned short A2 = f2bf(rA2);
                unsigned short B2 = f2bf(rB2);
                a0w[jp] = (unsigned int)A0 | ((unsigned int)B0 << 16);
                a1w[jp] = (unsigned int)A1 | ((unsigned int)B1 << 16);
                a2w[jp] = (unsigned int)A2 | ((unsigned int)B2 << 16);
            }
            // consume against all 8 column fragments (each B frag read once)
#pragma unroll
            for (int f = 0; f < 8; f++) {
                int fi = (f * 4 + ks) * 512 + lane * 8;
                sh8 b0 = *(const sh8*)&wfrag[fi];
                sh8 b1f = *(const sh8*)&wfrag[16384 + fi];
                sh8 b2f = *(const sh8*)&wfrag[32768 + fi];
                c[f] = MFMA(a0w, b0, c[f]);
                c[f] = MFMA(a1w, b0, c[f]);
                c[f] = MFMA(a2w, b0, c[f]);
                c[f] = MFMA(a0w, b1f, c[f]);
                c[f] = MFMA(a1w, b1f, c[f]);
                c[f] = MFMA(a0w, b2f, c[f]);
            }
        }
        // epilogue: softplus + W3 dot (component r = ray u*4+r, col n=f*16+m)
        float pr0 = 0.f, pr1 = 0.f, pr2 = 0.f, pr3 = 0.f;
#pragma unroll
        for (int f = 0; f < 8; f++) {
            float wv3 = w3v[f];
            pr0 = fmaf(sp_f(c[f].x), wv3, pr0);
            pr1 = fmaf(sp_f(c[f].y), wv3, pr1);
            pr2 = fmaf(sp_f(c[f].z), wv3, pr2);
            pr3 = fmaf(sp_f(c[f].w), wv3, pr3);
        }
        // reduce over the 16 m-lanes (n-dimension)
#pragma unroll
        for (int msk = 1; msk < 16; msk <<= 1) {
            pr0 += __shfl_xor(pr0, msk); pr1 += __shfl_xor(pr1, msk);
            pr2 += __shfl_xor(pr2, msk); pr3 += __shfl_xor(pr3, msk);
        }
        pr0 += b3v; pr1 += b3v; pr2 += b3v; pr3 += b3v;
        // redistribute: ray m lives at lane (m>>2)<<4, component m&3
        int srcl = (m >> 2) << 4;
        float q0 = __shfl(pr0, srcl), q1 = __shfl(pr1, srcl);
        float q2 = __shfl(pr2, srcl), q3 = __shfl(pr3, srcl);
        float sa = (m & 1) ? q1 : q0, sb = (m & 1) ? q3 : q2;
        sout = (m & 2) ? sb : sa;
    };

    // ---- sphere tracing ----
    float acc = nearv;
    bool unf = nearv < farv;
    bool dv = !unf;
    float sv;
#pragma unroll 1
    for (int it = 0; it < 32; ++it) {
        if (!__any((int)unf)) break;
        EVAL(acc, sv);
        float smv = fminf(fmaxf(sv, -0.1f), 0.1f);
        bool convu = unf;
        bool upd = unf && (fabsf(smv) > 1e-5f) && (fabsf(sv) < 1000000.0f);
        if (upd) acc = acc + smv;
        dv = upd ? (acc >= farv) : dv;
        bool remove = (convu && (fabsf(sv) <= 1e-5f)) || dv;
        unf = unf && !remove;
    }

    // ---- secant (last iteration is the final eval) ----
    float t0 = fminf(fmaxf(acc - 0.1f, nearv), farv);
    float t1 = fminf(fmaxf(acc, nearv), farv);
    float f0;
    EVAL(t0, f0);
    float f1 = 0.0f;
#pragma unroll 1
    for (int si = 0; si < 9; ++si) {
        float f1s;
        EVAL(t1, f1s);
        if (si == 8) { f1 = f1s; break; }
        float den = f0 - f1s;
        den = (fabsf(den) < 1e-9f) ? 1e-9f : den;
        float t2 = t1 - f1s * (t1 - t0) / den;
        t2 = fminf(fmaxf(t2, nearv), farv);
        t0 = t1; f0 = f1s; t1 = t2;
    }
    bool conv = (fabsf(f1) <= 1e-5f) && (t1 >= nearv) && (t1 <= farv);

    // xn at t1 (bit-identical to what EVAL computes internally)
    float xv0, xv1, xv2;
    {
        float y0 = fmaf(t1, dx, camx), y1 = fmaf(t1, dy, camy), y2 = fmaf(t1, dz, camz);
        xv0 = fmaf(y0, A[0], Bc[0]); xv1 = fmaf(y1, A[1], Bc[1]); xv2 = fmaf(y2, A[2], Bc[2]);
    }

    if (u == 0) {
        out[R * 3 + 0] = xv0;
        out[R * 3 + 1] = xv1;
        out[R * 3 + 2] = xv2;
        out[O1 + R] = conv ? 1.0f : 0.0f;
        out[O2 + R] = conv ? t1 : nearv;
        out[O6 + R] = conv ? 1.0f : 0.0f;
    }

    // ---- z samples: merge(sorted z_near, sorted z_far) if conv, else uniform ----
    float zreg[8];
    if (conv) {
        float a0v = t1 - 0.05f, sa = 0.1f / 15.0f;
        float b0v = nearv, sb = (farv - nearv) / 15.0f;
        int ia = 0, ib = 0;
#pragma unroll
        for (int i = 0; i < 32; i++) {
            float va = fmaf((float)ia, sa, a0v);
            float vb = fmaf((float)ib, sb, b0v);
            bool ta = (ia < 16) && ((ib >= 16) || (va <= vb));
            float zv = ta ? va : vb;
            if (ta) ia++; else ib++;
            if ((i >> 3) == u) zreg[i & 7] = zv;
        }
    } else {
        float rng = farv - nearv;
#pragma unroll
        for (int q = 0; q < 8; q++) {
            int i = u * 8 + q;
            zreg[q] = fmaf((float)i * (1.0f / 31.0f), rng, nearv);
        }
    }

    // dists
    {
        f4 d0, d1;
#pragma unroll
        for (int q = 0; q < 4; q++) { d0[q] = zreg[q]; d1[q] = zreg[4 + q]; }
        *(f4*)&out[O4 + R * 32 + u * 8] = d0;
        *(f4*)&out[O4 + R * 32 + u * 8 + 4] = d1;
    }

    // points
    {
        f4 pk[6];
#pragma unroll
        for (int q = 0; q < 8; q++) {
            float z = zreg[q];
            float y0 = fmaf(z, dx, camx), y1 = fmaf(z, dy, camy), y2 = fmaf(z, dz, camz);
            float v0 = fmaf(y0, A[0], Bc[0]);
            float v1 = fmaf(y1, A[1], Bc[1]);
            float v2 = fmaf(y2, A[2], Bc[2]);
#pragma unroll
            for (int c = 0; c < 3; c++) {
                int ee = q * 3 + c;
                float vv = (c == 0) ? v0 : ((c == 1) ? v1 : v2);
                pk[ee >> 2][ee & 3] = vv;
            }
        }
        int pbase = O3 + R * 96 + u * 24;
#pragma unroll
        for (int s6 = 0; s6 < 6; s6++) *(f4*)&out[pbase + s6 * 4] = pk[s6];
    }

    // ---- sampler_transforms: broadcast T rows, coalesced per wave ----
    {
        f4 myrow = *(const f4*)&Tmat[(lane & 3) * 4];
        int base = O5 + rayBase * 512;
#pragma unroll
        for (int cc = 0; cc < 32; cc++) {
            int g = lane + 64 * cc;
            *(f4*)&out[base + g * 4] = myrow;
        }
    }
}

extern "C" void kernel_launch(void* const* d_in, const int* in_sizes, int n_in,
                              void* d_out, int out_size, void* d_ws, size_t ws_size,
                              hipStream_t stream) {
    (void)n_in; (void)out_size; (void)ws_size;
    const float* cam  = (const float*)d_in[0];
    const float* dirs = (const float*)d_in[1];
    const float* bbi  = (const float*)d_in[2];
    const float* loc  = (const float*)d_in[3];
    const float* scf  = (const float*)d_in[4];
    const float* sw   = (const float*)d_in[7];
    const float* bt   = (const float*)d_in[8];
    const float* trn  = (const float*)d_in[9];
    const float* cmn  = (const float*)d_in[10];
    const float* cmx  = (const float*)d_in[11];
    const float* cen  = (const float*)d_in[12];
    const float* W1   = (const float*)d_in[13];
    const float* b1   = (const float*)d_in[14];
    const float* W2   = (const float*)d_in[15];
    const float* b2   = (const float*)d_in[16];
    const float* W3   = (const float*)d_in[17];
    const float* b3   = (const float*)d_in[18];

    float* Tout = (float*)d_ws;
    int N = in_sizes[1] / 3;
    int V = in_sizes[7] / 24;

    hipLaunchKernelGGL(t_kernel, dim3(1), dim3(256), 0, stream, sw, bt, Tout, V);
    hipLaunchKernelGGL(main_kernel, dim3(N / 64), dim3(256), 0, stream,
                       cam, dirs, bbi, loc, scf, trn, cmn, cmx, cen,
                       W1, b1, W2, b2, W3, b3, Tout,
                       (float*)d_out, N);
}

// Round 7
// 497.476 us; speedup vs baseline: 2.2414x; 1.8476x over previous
//
#include <hip/hip_runtime.h>

typedef short sh8 __attribute__((ext_vector_type(8)));
typedef __bf16 bf8 __attribute__((ext_vector_type(8)));
typedef float f4 __attribute__((ext_vector_type(4)));
typedef unsigned int u4 __attribute__((ext_vector_type(4)));

#define DEV __device__ __forceinline__

DEV unsigned int fbits(float f){ union{float f;unsigned int u;}v; v.f=f; return v.u; }
DEV float bitsf(unsigned int u){ union{unsigned int u;float f;}v; v.u=u; return v.f; }
DEV float bf2f(unsigned short u) { return bitsf(((unsigned int)u) << 16); }
// RTNE f32->bf16 (proven numerics rounds 2/4/5/6 — DO NOT CHANGE)
DEV unsigned short f2bf(float f) {
    unsigned int x = fbits(f);
    return (unsigned short)((x + 0x7fffu + ((x >> 16) & 1u)) >> 16);
}
// softplus(x) = max(x,0) + log1p(exp(-|x|)) — branch-free native-op inline:
//   e = 2^(-|x|*log2e)            (v_exp_f32, 1 mul)
//   u = 1+e; c = e-(u-1)          (Sterbenz: c exact, captures the 1+e rounding)
//   log1p(e) = ln2*log2(u) + c/u,  c/u ~= c*(2-u)  (err <= 2^-26)
// worst-case |delta vs ocml| ~1.3e-7 abs; typical ~5e-8.
DEV float sp_f(float x) {
    float ax = fabsf(x);
    float e  = exp2f(ax * -1.4426950408889634f);
    float u  = 1.0f + e;
    float c  = e - (u - 1.0f);
    float lg = log2f(u);
    return fmaxf(x, 0.0f) + fmaf(0.69314718055994531f, lg, c * (2.0f - u));
}

#define MFMA(a, b, c) __builtin_amdgcn_mfma_f32_16x16x32_bf16(__builtin_bit_cast(bf8, a), __builtin_bit_cast(bf8, b), c, 0, 0, 0)

// ---------------- T = einsum(w_mean_norm, bone_transforms) ----------------
__global__ void t_kernel(const float* __restrict__ sw,
                         const float* __restrict__ bt,
                         float* __restrict__ Tout, int V) {
    __shared__ float red[4 * 24];
    __shared__ float mm[24];
    float p[24];
#pragma unroll
    for (int j = 0; j < 24; j++) p[j] = 0.0f;
    for (int v = threadIdx.x; v < V; v += 256) {
        const float* row = sw + v * 24;
#pragma unroll
        for (int c4 = 0; c4 < 6; c4++) {
            f4 a = *(const f4*)(row + c4 * 4);
#pragma unroll
            for (int e = 0; e < 4; e++) p[c4 * 4 + e] += a[e];
        }
    }
#pragma unroll
    for (int j = 0; j < 24; j++) {
#pragma unroll
        for (int msk = 1; msk < 64; msk <<= 1) p[j] += __shfl_xor(p[j], msk);
    }
    int lane = threadIdx.x & 63, wid = threadIdx.x >> 6;
    if (lane == 0) {
#pragma unroll
        for (int j = 0; j < 24; j++) red[wid * 24 + j] = p[j];
    }
    __syncthreads();
    if (threadIdx.x < 24) {
        float s = red[threadIdx.x] + red[24 + threadIdx.x] + red[48 + threadIdx.x] + red[72 + threadIdx.x];
        mm[threadIdx.x] = s / (float)V;
    }
    __syncthreads();
    if (threadIdx.x < 16) {
        float tot = 0.0f;
#pragma unroll
        for (int j = 0; j < 24; j++) tot += mm[j];
        float a = 0.0f;
#pragma unroll
        for (int j = 0; j < 24; j++) a += (mm[j] / tot) * bt[j * 16 + threadIdx.x];
        Tout[threadIdx.x] = a;
    }
}

// ---------------- main: trace + secant + sample ----------------
// wave = 16 rays; lane l: ray m = l&15, k-slice u = l>>4
// W2^T as 3 RTNE-split bf16 copies in FRAGMENT-CONTIGUOUS LDS:
//   frag fi=(nt*4+ks): lane l holds B[k=ks*32+(l>>4)*8+j][n=nt*16+(l&15)], j=0..7
//   u16 offset = split*16384 + fi*512 + l*8 + j  -> ds_read_b128 conflict-free
// EVAL is ks-outer: A-split words for one k-slice produced just-in-time and
// consumed immediately -> minimal live set.
__global__ __launch_bounds__(256, 1) void main_kernel(
    const float* __restrict__ cam_loc, const float* __restrict__ dirs,
    const float* __restrict__ bbi,     const float* __restrict__ loc,
    const float* __restrict__ scf,     const float* __restrict__ trans,
    const float* __restrict__ cmin,    const float* __restrict__ cmax,
    const float* __restrict__ cent,    const float* __restrict__ W1,
    const float* __restrict__ b1,      const float* __restrict__ W2,
    const float* __restrict__ b2,      const float* __restrict__ W3,
    const float* __restrict__ b3,      const float* __restrict__ Tmat,
    float* __restrict__ out, int N) {

    __shared__ unsigned short wfrag[3 * 16384];   // 96 KB
    __shared__ f4 w1p[16 * 9];                    // stride-9 pad
    __shared__ float b2s[128], w3s[128];

    const int tid = threadIdx.x;

    // ---- stage W2 (f32) -> 3 RTNE splits, fragment order (bit-exact) ----
    for (int i4 = tid; i4 < 4096; i4 += 256) {
        f4 v = *(const f4*)(W2 + i4 * 4);
        int k = (i4 * 4) >> 7;          // same k for all 4 elems (128 % 4 == 0)
        int n0 = (i4 * 4) & 127;
        int lanehalf = ((k >> 3) & 3) << 4;
        int fk = k >> 5;
        int j = k & 7;
#pragma unroll
        for (int e = 0; e < 4; e++) {
            int n = n0 + e;
            float w = v[e];
            unsigned short u0 = f2bf(w);   float g0 = bf2f(u0);
            float r1 = w - g0;             unsigned short u1 = f2bf(r1); float g1 = bf2f(u1);
            float r2 = r1 - g1;            unsigned short u2 = f2bf(r2);
            int off = ((n >> 4) * 4 + fk) * 512 + (lanehalf | (n & 15)) * 8 + j;
            wfrag[off]         = u0;
            wfrag[16384 + off] = u1;
            wfrag[32768 + off] = u2;
        }
    }
    if (tid < 128) {
        int k = tid, ks = k >> 5, uu = (k >> 3) & 3, j = k & 7;
        f4 w;
        w.x = W1[k]; w.y = W1[128 + k]; w.z = W1[256 + k]; w.w = b1[k];
        w1p[(ks * 4 + uu) * 9 + j] = w;
        b2s[k] = b2[k];
        w3s[k] = W3[k];
    }
    __syncthreads();   // last block-wide sync

    const int lane = tid & 63;
    const int wv = tid >> 6;
    const int m = lane & 15, u = lane >> 4;
    const int rayBase = (blockIdx.x * 4 + wv) * 16;
    const int R = rayBase + m;

    const int O1 = 3 * N, O2 = 4 * N, O3 = 5 * N, O4 = 101 * N, O5 = 133 * N, O6 = 645 * N;

    float camx = cam_loc[0], camy = cam_loc[1], camz = cam_loc[2];
    float A[3], Bc[3];
#pragma unroll
    for (int c = 0; c < 3; c++) {
        float he = 0.5f * (cmax[c] - cmin[c]);
        float sc = scf[c];
        float off = (0.0f - trans[c] - loc[c]) * sc - cent[c];
        A[c] = sc / he; Bc[c] = off / he;
    }
    float dx = dirs[R * 3 + 0], dy = dirs[R * 3 + 1], dz = dirs[R * 3 + 2];
    float nearv = bbi[R * 2 + 0], farv = bbi[R * 2 + 1];

    float w3v[8], b2v[8];
#pragma unroll
    for (int nt = 0; nt < 8; nt++) { w3v[nt] = w3s[nt * 16 + m]; b2v[nt] = b2s[nt * 16 + m]; }
    float b3v = b3[0];

    // ---- one SDF eval at t; returns s only ----
    auto EVAL = [&](float t, float& sout) {
        float y0 = fmaf(t, dx, camx), y1 = fmaf(t, dy, camy), y2 = fmaf(t, dz, camz);
        float x0 = fmaf(y0, A[0], Bc[0]), x1 = fmaf(y1, A[1], Bc[1]), x2 = fmaf(y2, A[2], Bc[2]);
        f4 c[8];
#pragma unroll
        for (int f = 0; f < 8; f++) {
            float b = b2v[f];
            c[f] = (f4){b, b, b, b};
        }
#pragma unroll
        for (int ks = 0; ks < 4; ks++) {
            // A-split words for this k-slice (8 neurons -> 4 words per split)
            u4 a0w, a1w, a2w;
#pragma unroll
            for (int jp = 0; jp < 4; jp++) {
                f4 wA = w1p[(ks * 4 + u) * 9 + 2 * jp];
                f4 wB = w1p[(ks * 4 + u) * 9 + 2 * jp + 1];
                float hA = fmaf(x0, wA.x, fmaf(x1, wA.y, fmaf(x2, wA.z, wA.w)));
                float hB = fmaf(x0, wB.x, fmaf(x1, wB.y, fmaf(x2, wB.z, wB.w)));
                float sA = sp_f(hA), sB = sp_f(hB);
                unsigned short A0 = f2bf(sA); float fA0 = bf2f(A0);
                unsigned short B0 = f2bf(sB); float fB0 = bf2f(B0);
                float rA1 = sA - fA0, rB1 = sB - fB0;
                unsigned short A1 = f2bf(rA1); float fA1 = bf2f(A1);
                unsigned short B1 = f2bf(rB1); float fB1 = bf2f(B1);
                float rA2 = rA1 - fA1, rB2 = rB1 - fB1;
                unsigned short A2 = f2bf(rA2);
                unsigned short B2 = f2bf(rB2);
                a0w[jp] = (unsigned int)A0 | ((unsigned int)B0 << 16);
                a1w[jp] = (unsigned int)A1 | ((unsigned int)B1 << 16);
                a2w[jp] = (unsigned int)A2 | ((unsigned int)B2 << 16);
            }
            // consume against all 8 column fragments (each B frag read once)
#pragma unroll
            for (int f = 0; f < 8; f++) {
                int fi = (f * 4 + ks) * 512 + lane * 8;
                sh8 b0 = *(const sh8*)&wfrag[fi];
                sh8 b1f = *(const sh8*)&wfrag[16384 + fi];
                sh8 b2f = *(const sh8*)&wfrag[32768 + fi];
                c[f] = MFMA(a0w, b0, c[f]);
                c[f] = MFMA(a1w, b0, c[f]);
                c[f] = MFMA(a2w, b0, c[f]);
                c[f] = MFMA(a0w, b1f, c[f]);
                c[f] = MFMA(a1w, b1f, c[f]);
                c[f] = MFMA(a0w, b2f, c[f]);
            }
        }
        // epilogue: softplus + W3 dot (component r = ray u*4+r, col n=f*16+m)
        float pr0 = 0.f, pr1 = 0.f, pr2 = 0.f, pr3 = 0.f;
#pragma unroll
        for (int f = 0; f < 8; f++) {
            float wv3 = w3v[f];
            pr0 = fmaf(sp_f(c[f].x), wv3, pr0);
            pr1 = fmaf(sp_f(c[f].y), wv3, pr1);
            pr2 = fmaf(sp_f(c[f].z), wv3, pr2);
            pr3 = fmaf(sp_f(c[f].w), wv3, pr3);
        }
        // reduce over the 16 m-lanes (n-dimension)
#pragma unroll
        for (int msk = 1; msk < 16; msk <<= 1) {
            pr0 += __shfl_xor(pr0, msk); pr1 += __shfl_xor(pr1, msk);
            pr2 += __shfl_xor(pr2, msk); pr3 += __shfl_xor(pr3, msk);
        }
        pr0 += b3v; pr1 += b3v; pr2 += b3v; pr3 += b3v;
        // redistribute: ray m lives at lane (m>>2)<<4, component m&3
        int srcl = (m >> 2) << 4;
        float q0 = __shfl(pr0, srcl), q1 = __shfl(pr1, srcl);
        float q2 = __shfl(pr2, srcl), q3 = __shfl(pr3, srcl);
        float sa = (m & 1) ? q1 : q0, sb = (m & 1) ? q3 : q2;
        sout = (m & 2) ? sb : sa;
    };

    // ---- sphere tracing ----
    float acc = nearv;
    bool unf = nearv < farv;
    bool dv = !unf;
    float sv;
#pragma unroll 1
    for (int it = 0; it < 32; ++it) {
        if (!__any((int)unf)) break;
        EVAL(acc, sv);
        float smv = fminf(fmaxf(sv, -0.1f), 0.1f);
        bool convu = unf;
        bool upd = unf && (fabsf(smv) > 1e-5f) && (fabsf(sv) < 1000000.0f);
        if (upd) acc = acc + smv;
        dv = upd ? (acc >= farv) : dv;
        bool remove = (convu && (fabsf(sv) <= 1e-5f)) || dv;
        unf = unf && !remove;
    }

    // ---- secant (last iteration is the final eval) ----
    float t0 = fminf(fmaxf(acc - 0.1f, nearv), farv);
    float t1 = fminf(fmaxf(acc, nearv), farv);
    float f0;
    EVAL(t0, f0);
    float f1 = 0.0f;
#pragma unroll 1
    for (int si = 0; si < 9; ++si) {
        float f1s;
        EVAL(t1, f1s);
        if (si == 8) { f1 = f1s; break; }
        float den = f0 - f1s;
        den = (fabsf(den) < 1e-9f) ? 1e-9f : den;
        float t2 = t1 - f1s * (t1 - t0) / den;
        t2 = fminf(fmaxf(t2, nearv), farv);
        t0 = t1; f0 = f1s; t1 = t2;
    }
    bool conv = (fabsf(f1) <= 1e-5f) && (t1 >= nearv) && (t1 <= farv);

    // xn at t1 (bit-identical to what EVAL computes internally)
    float xv0, xv1, xv2;
    {
        float y0 = fmaf(t1, dx, camx), y1 = fmaf(t1, dy, camy), y2 = fmaf(t1, dz, camz);
        xv0 = fmaf(y0, A[0], Bc[0]); xv1 = fmaf(y1, A[1], Bc[1]); xv2 = fmaf(y2, A[2], Bc[2]);
    }

    if (u == 0) {
        out[R * 3 + 0] = xv0;
        out[R * 3 + 1] = xv1;
        out[R * 3 + 2] = xv2;
        out[O1 + R] = conv ? 1.0f : 0.0f;
        out[O2 + R] = conv ? t1 : nearv;
        out[O6 + R] = conv ? 1.0f : 0.0f;
    }

    // ---- z samples: merge(sorted z_near, sorted z_far) if conv, else uniform ----
    float zreg[8];
    if (conv) {
        float a0v = t1 - 0.05f, sa = 0.1f / 15.0f;
        float b0v = nearv, sb = (farv - nearv) / 15.0f;
        int ia = 0, ib = 0;
#pragma unroll
        for (int i = 0; i < 32; i++) {
            float va = fmaf((float)ia, sa, a0v);
            float vb = fmaf((float)ib, sb, b0v);
            bool ta = (ia < 16) && ((ib >= 16) || (va <= vb));
            float zv = ta ? va : vb;
            if (ta) ia++; else ib++;
            if ((i >> 3) == u) zreg[i & 7] = zv;
        }
    } else {
        float rng = farv - nearv;
#pragma unroll
        for (int q = 0; q < 8; q++) {
            int i = u * 8 + q;
            zreg[q] = fmaf((float)i * (1.0f / 31.0f), rng, nearv);
        }
    }

    // dists
    {
        f4 d0, d1;
#pragma unroll
        for (int q = 0; q < 4; q++) { d0[q] = zreg[q]; d1[q] = zreg[4 + q]; }
        *(f4*)&out[O4 + R * 32 + u * 8] = d0;
        *(f4*)&out[O4 + R * 32 + u * 8 + 4] = d1;
    }

    // points
    {
        f4 pk[6];
#pragma unroll
        for (int q = 0; q < 8; q++) {
            float z = zreg[q];
            float y0 = fmaf(z, dx, camx), y1 = fmaf(z, dy, camy), y2 = fmaf(z, dz, camz);
            float v0 = fmaf(y0, A[0], Bc[0]);
            float v1 = fmaf(y1, A[1], Bc[1]);
            float v2 = fmaf(y2, A[2], Bc[2]);
#pragma unroll
            for (int c = 0; c < 3; c++) {
                int ee = q * 3 + c;
                float vv = (c == 0) ? v0 : ((c == 1) ? v1 : v2);
                pk[ee >> 2][ee & 3] = vv;
            }
        }
        int pbase = O3 + R * 96 + u * 24;
#pragma unroll
        for (int s6 = 0; s6 < 6; s6++) *(f4*)&out[pbase + s6 * 4] = pk[s6];
    }

    // ---- sampler_transforms: broadcast T rows, coalesced per wave ----
    {
        f4 myrow = *(const f4*)&Tmat[(lane & 3) * 4];
        int base = O5 + rayBase * 512;
#pragma unroll
        for (int cc = 0; cc < 32; cc++) {
            int g = lane + 64 * cc;
            *(f4*)&out[base + g * 4] = myrow;
        }
    }
}

extern "C" void kernel_launch(void* const* d_in, const int* in_sizes, int n_in,
                              void* d_out, int out_size, void* d_ws, size_t ws_size,
                              hipStream_t stream) {
    (void)n_in; (void)out_size; (void)ws_size;
    const float* cam  = (const float*)d_in[0];
    const float* dirs = (const float*)d_in[1];
    const float* bbi  = (const float*)d_in[2];
    const float* loc  = (const float*)d_in[3];
    const float* scf  = (const float*)d_in[4];
    const float* sw   = (const float*)d_in[7];
    const float* bt   = (const float*)d_in[8];
    const float* trn  = (const float*)d_in[9];
    const float* cmn  = (const float*)d_in[10];
    const float* cmx  = (const float*)d_in[11];
    const float* cen  = (const float*)d_in[12];
    const float* W1   = (const float*)d_in[13];
    const float* b1   = (const float*)d_in[14];
    const float* W2   = (const float*)d_in[15];
    const float* b2   = (const float*)d_in[16];
    const float* W3   = (const float*)d_in[17];
    const float* b3   = (const float*)d_in[18];

    float* Tout = (float*)d_ws;
    int N = in_sizes[1] / 3;
    int V = in_sizes[7] / 24;

    hipLaunchKernelGGL(t_kernel, dim3(1), dim3(256), 0, stream, sw, bt, Tout, V);
    hipLaunchKernelGGL(main_kernel, dim3(N / 64), dim3(256), 0, stream,
                       cam, dirs, bbi, loc, scf, trn, cmn, cmx, cen,
                       W1, b1, W2, b2, W3, b3, Tout,
                       (float*)d_out, N);
}

// Round 8
// 377.506 us; speedup vs baseline: 2.9537x; 1.3178x over previous
//
#include <hip/hip_runtime.h>

typedef short sh8 __attribute__((ext_vector_type(8)));
typedef __bf16 bf8 __attribute__((ext_vector_type(8)));
typedef float f4 __attribute__((ext_vector_type(4)));
typedef unsigned int u4 __attribute__((ext_vector_type(4)));

#define DEV __device__ __forceinline__

DEV unsigned int fbits(float f){ union{float f;unsigned int u;}v; v.f=f; return v.u; }
DEV float bitsf(unsigned int u){ union{unsigned int u;float f;}v; v.u=u; return v.f; }
DEV float bf2f(unsigned short u) { return bitsf(((unsigned int)u) << 16); }
// RTNE f32->bf16 (proven numerics rounds 2/4/5/6/7 — DO NOT CHANGE)
DEV unsigned short f2bf(float f) {
    unsigned int x = fbits(f);
    return (unsigned short)((x + 0x7fffu + ((x >> 16) & 1u)) >> 16);
}
// softplus — branch-free native-op inline (proven round 7 — DO NOT CHANGE)
DEV float sp_f(float x) {
    float ax = fabsf(x);
    float e  = exp2f(ax * -1.4426950408889634f);
    float u  = 1.0f + e;
    float c  = e - (u - 1.0f);
    float lg = log2f(u);
    return fmaxf(x, 0.0f) + fmaf(0.69314718055994531f, lg, c * (2.0f - u));
}

#define MFMA(a, b, c) __builtin_amdgcn_mfma_f32_16x16x32_bf16(__builtin_bit_cast(bf8, a), __builtin_bit_cast(bf8, b), c, 0, 0, 0)

// ---------------- T = einsum(w_mean_norm, bone_transforms) ----------------
__global__ void t_kernel(const float* __restrict__ sw,
                         const float* __restrict__ bt,
                         float* __restrict__ Tout, int V) {
    __shared__ float red[4 * 24];
    __shared__ float mm[24];
    float p[24];
#pragma unroll
    for (int j = 0; j < 24; j++) p[j] = 0.0f;
    for (int v = threadIdx.x; v < V; v += 256) {
        const float* row = sw + v * 24;
#pragma unroll
        for (int c4 = 0; c4 < 6; c4++) {
            f4 a = *(const f4*)(row + c4 * 4);
#pragma unroll
            for (int e = 0; e < 4; e++) p[c4 * 4 + e] += a[e];
        }
    }
#pragma unroll
    for (int j = 0; j < 24; j++) {
#pragma unroll
        for (int msk = 1; msk < 64; msk <<= 1) p[j] += __shfl_xor(p[j], msk);
    }
    int lane = threadIdx.x & 63, wid = threadIdx.x >> 6;
    if (lane == 0) {
#pragma unroll
        for (int j = 0; j < 24; j++) red[wid * 24 + j] = p[j];
    }
    __syncthreads();
    if (threadIdx.x < 24) {
        float s = red[threadIdx.x] + red[24 + threadIdx.x] + red[48 + threadIdx.x] + red[72 + threadIdx.x];
        mm[threadIdx.x] = s / (float)V;
    }
    __syncthreads();
    if (threadIdx.x < 16) {
        float tot = 0.0f;
#pragma unroll
        for (int j = 0; j < 24; j++) tot += mm[j];
        float a = 0.0f;
#pragma unroll
        for (int j = 0; j < 24; j++) a += (mm[j] / tot) * bt[j * 16 + threadIdx.x];
        Tout[threadIdx.x] = a;
    }
}

// ---------------- main: trace + secant + sample ----------------
// wave = 16 rays; lane l: ray m = l&15, k-slice u = l>>4
// W2^T as 3 RTNE-split bf16 copies in FRAGMENT-CONTIGUOUS LDS:
//   frag fi=(nt*4+ks): lane l holds B[k=ks*32+(l>>4)*8+j][n=nt*16+(l&15)], j=0..7
//   u16 offset = split*16384 + fi*512 + l*8 + j  -> ds_read_b128 conflict-free
// EVAL: ks-loop kept ROLLED (#pragma unroll 1) — backedge caps scheduler
// hoisting so live pressure stays ~120 regs (anti-spill).
__global__ __launch_bounds__(256, 1) void main_kernel(
    const float* __restrict__ cam_loc, const float* __restrict__ dirs,
    const float* __restrict__ bbi,     const float* __restrict__ loc,
    const float* __restrict__ scf,     const float* __restrict__ trans,
    const float* __restrict__ cmin,    const float* __restrict__ cmax,
    const float* __restrict__ cent,    const float* __restrict__ W1,
    const float* __restrict__ b1,      const float* __restrict__ W2,
    const float* __restrict__ b2,      const float* __restrict__ W3,
    const float* __restrict__ b3,      const float* __restrict__ Tmat,
    float* __restrict__ out, int N) {

    __shared__ unsigned short wfrag[3 * 16384];   // 96 KB
    __shared__ f4 w1p[16 * 9];                    // stride-9 pad
    __shared__ float b2s[128], w3s[128];

    const int tid = threadIdx.x;

    // ---- stage W2 (f32) -> 3 RTNE splits, fragment order (bit-exact) ----
    for (int i4 = tid; i4 < 4096; i4 += 256) {
        f4 v = *(const f4*)(W2 + i4 * 4);
        int k = (i4 * 4) >> 7;          // same k for all 4 elems (128 % 4 == 0)
        int n0 = (i4 * 4) & 127;
        int lanehalf = ((k >> 3) & 3) << 4;
        int fk = k >> 5;
        int j = k & 7;
#pragma unroll
        for (int e = 0; e < 4; e++) {
            int n = n0 + e;
            float w = v[e];
            unsigned short u0 = f2bf(w);   float g0 = bf2f(u0);
            float r1 = w - g0;             unsigned short u1 = f2bf(r1); float g1 = bf2f(u1);
            float r2 = r1 - g1;            unsigned short u2 = f2bf(r2);
            int off = ((n >> 4) * 4 + fk) * 512 + (lanehalf | (n & 15)) * 8 + j;
            wfrag[off]         = u0;
            wfrag[16384 + off] = u1;
            wfrag[32768 + off] = u2;
        }
    }
    if (tid < 128) {
        int k = tid, ks = k >> 5, uu = (k >> 3) & 3, j = k & 7;
        f4 w;
        w.x = W1[k]; w.y = W1[128 + k]; w.z = W1[256 + k]; w.w = b1[k];
        w1p[(ks * 4 + uu) * 9 + j] = w;
        b2s[k] = b2[k];
        w3s[k] = W3[k];
    }
    __syncthreads();   // last block-wide sync

    const int lane = tid & 63;
    const int wv = tid >> 6;
    const int m = lane & 15, u = lane >> 4;
    const int rayBase = (blockIdx.x * 4 + wv) * 16;
    const int R = rayBase + m;

    const int O1 = 3 * N, O2 = 4 * N, O3 = 5 * N, O4 = 101 * N, O5 = 133 * N, O6 = 645 * N;

    float camx = cam_loc[0], camy = cam_loc[1], camz = cam_loc[2];
    float A[3], Bc[3];
#pragma unroll
    for (int c = 0; c < 3; c++) {
        float he = 0.5f * (cmax[c] - cmin[c]);
        float sc = scf[c];
        float off = (0.0f - trans[c] - loc[c]) * sc - cent[c];
        A[c] = sc / he; Bc[c] = off / he;
    }
    float dx = dirs[R * 3 + 0], dy = dirs[R * 3 + 1], dz = dirs[R * 3 + 2];
    float nearv = bbi[R * 2 + 0], farv = bbi[R * 2 + 1];

    float w3v[8], b2v[8];
#pragma unroll
    for (int nt = 0; nt < 8; nt++) { w3v[nt] = w3s[nt * 16 + m]; b2v[nt] = b2s[nt * 16 + m]; }
    float b3v = b3[0];

    const int lane16 = lane * 8;   // u16 elements; *2 bytes = lane*16B

    // ---- one SDF eval at t; returns s only ----
    auto EVAL = [&](float t, float& sout) {
        float y0 = fmaf(t, dx, camx), y1 = fmaf(t, dy, camy), y2 = fmaf(t, dz, camz);
        float x0 = fmaf(y0, A[0], Bc[0]), x1 = fmaf(y1, A[1], Bc[1]), x2 = fmaf(y2, A[2], Bc[2]);
        f4 c[8];
#pragma unroll
        for (int f = 0; f < 8; f++) {
            float b = b2v[f];
            c[f] = (f4){b, b, b, b};
        }
#pragma unroll 1
        for (int ks = 0; ks < 4; ks++) {
            // A-split words for this k-slice (8 neurons -> 4 words per split)
            u4 a0w, a1w, a2w;
#pragma unroll
            for (int jp = 0; jp < 4; jp++) {
                f4 wA = w1p[(ks * 4 + u) * 9 + 2 * jp];
                f4 wB = w1p[(ks * 4 + u) * 9 + 2 * jp + 1];
                float hA = fmaf(x0, wA.x, fmaf(x1, wA.y, fmaf(x2, wA.z, wA.w)));
                float hB = fmaf(x0, wB.x, fmaf(x1, wB.y, fmaf(x2, wB.z, wB.w)));
                float sA = sp_f(hA), sB = sp_f(hB);
                unsigned short A0 = f2bf(sA); float fA0 = bf2f(A0);
                unsigned short B0 = f2bf(sB); float fB0 = bf2f(B0);
                float rA1 = sA - fA0, rB1 = sB - fB0;
                unsigned short A1 = f2bf(rA1); float fA1 = bf2f(A1);
                unsigned short B1 = f2bf(rB1); float fB1 = bf2f(B1);
                float rA2 = rA1 - fA1, rB2 = rB1 - fB1;
                unsigned short A2 = f2bf(rA2);
                unsigned short B2 = f2bf(rB2);
                a0w[jp] = (unsigned int)A0 | ((unsigned int)B0 << 16);
                a1w[jp] = (unsigned int)A1 | ((unsigned int)B1 << 16);
                a2w[jp] = (unsigned int)A2 | ((unsigned int)B2 << 16);
            }
            // consume against all 8 column fragments (each B frag read once)
            const int base = ks * 512 + lane16;
#pragma unroll
            for (int f = 0; f < 8; f++) {
                int fi = f * 2048 + base;
                sh8 b0 = *(const sh8*)&wfrag[fi];
                sh8 b1f = *(const sh8*)&wfrag[16384 + fi];
                sh8 b2f = *(const sh8*)&wfrag[32768 + fi];
                c[f] = MFMA(a0w, b0, c[f]);
                c[f] = MFMA(a1w, b0, c[f]);
                c[f] = MFMA(a2w, b0, c[f]);
                c[f] = MFMA(a0w, b1f, c[f]);
                c[f] = MFMA(a1w, b1f, c[f]);
                c[f] = MFMA(a0w, b2f, c[f]);
            }
        }
        // epilogue: softplus + W3 dot (component r = ray u*4+r, col n=f*16+m)
        float pr0 = 0.f, pr1 = 0.f, pr2 = 0.f, pr3 = 0.f;
#pragma unroll
        for (int f = 0; f < 8; f++) {
            float wv3 = w3v[f];
            pr0 = fmaf(sp_f(c[f].x), wv3, pr0);
            pr1 = fmaf(sp_f(c[f].y), wv3, pr1);
            pr2 = fmaf(sp_f(c[f].z), wv3, pr2);
            pr3 = fmaf(sp_f(c[f].w), wv3, pr3);
        }
        // reduce over the 16 m-lanes (n-dimension)
#pragma unroll
        for (int msk = 1; msk < 16; msk <<= 1) {
            pr0 += __shfl_xor(pr0, msk); pr1 += __shfl_xor(pr1, msk);
            pr2 += __shfl_xor(pr2, msk); pr3 += __shfl_xor(pr3, msk);
        }
        pr0 += b3v; pr1 += b3v; pr2 += b3v; pr3 += b3v;
        // redistribute: ray m lives at lane (m>>2)<<4, component m&3
        int srcl = (m >> 2) << 4;
        float q0 = __shfl(pr0, srcl), q1 = __shfl(pr1, srcl);
        float q2 = __shfl(pr2, srcl), q3 = __shfl(pr3, srcl);
        float sa = (m & 1) ? q1 : q0, sb = (m & 1) ? q3 : q2;
        sout = (m & 2) ? sb : sa;
    };

    // ---- sphere tracing ----
    float acc = nearv;
    bool unf = nearv < farv;
    bool dv = !unf;
    float sv;
#pragma unroll 1
    for (int it = 0; it < 32; ++it) {
        if (!__any((int)unf)) break;
        EVAL(acc, sv);
        float smv = fminf(fmaxf(sv, -0.1f), 0.1f);
        bool convu = unf;
        bool upd = unf && (fabsf(smv) > 1e-5f) && (fabsf(sv) < 1000000.0f);
        if (upd) acc = acc + smv;
        dv = upd ? (acc >= farv) : dv;
        bool remove = (convu && (fabsf(sv) <= 1e-5f)) || dv;
        unf = unf && !remove;
    }

    // ---- secant (last iteration is the final eval) ----
    float t0 = fminf(fmaxf(acc - 0.1f, nearv), farv);
    float t1 = fminf(fmaxf(acc, nearv), farv);
    float f0;
    EVAL(t0, f0);
    float f1 = 0.0f;
#pragma unroll 1
    for (int si = 0; si < 9; ++si) {
        float f1s;
        EVAL(t1, f1s);
        if (si == 8) { f1 = f1s; break; }
        float den = f0 - f1s;
        den = (fabsf(den) < 1e-9f) ? 1e-9f : den;
        float t2 = t1 - f1s * (t1 - t0) / den;
        t2 = fminf(fmaxf(t2, nearv), farv);
        t0 = t1; f0 = f1s; t1 = t2;
    }
    bool conv = (fabsf(f1) <= 1e-5f) && (t1 >= nearv) && (t1 <= farv);

    // xn at t1 (bit-identical to what EVAL computes internally)
    float xv0, xv1, xv2;
    {
        float y0 = fmaf(t1, dx, camx), y1 = fmaf(t1, dy, camy), y2 = fmaf(t1, dz, camz);
        xv0 = fmaf(y0, A[0], Bc[0]); xv1 = fmaf(y1, A[1], Bc[1]); xv2 = fmaf(y2, A[2], Bc[2]);
    }

    if (u == 0) {
        out[R * 3 + 0] = xv0;
        out[R * 3 + 1] = xv1;
        out[R * 3 + 2] = xv2;
        out[O1 + R] = conv ? 1.0f : 0.0f;
        out[O2 + R] = conv ? t1 : nearv;
        out[O6 + R] = conv ? 1.0f : 0.0f;
    }

    // ---- z samples: merge(sorted z_near, sorted z_far) if conv, else uniform ----
    float zreg[8];
    if (conv) {
        float a0v = t1 - 0.05f, sa = 0.1f / 15.0f;
        float b0v = nearv, sb = (farv - nearv) / 15.0f;
        int ia = 0, ib = 0;
#pragma unroll
        for (int i = 0; i < 32; i++) {
            float va = fmaf((float)ia, sa, a0v);
            float vb = fmaf((float)ib, sb, b0v);
            bool ta = (ia < 16) && ((ib >= 16) || (va <= vb));
            float zv = ta ? va : vb;
            if (ta) ia++; else ib++;
            if ((i >> 3) == u) zreg[i & 7] = zv;
        }
    } else {
        float rng = farv - nearv;
#pragma unroll
        for (int q = 0; q < 8; q++) {
            int i = u * 8 + q;
            zreg[q] = fmaf((float)i * (1.0f / 31.0f), rng, nearv);
        }
    }

    // dists
    {
        f4 d0, d1;
#pragma unroll
        for (int q = 0; q < 4; q++) { d0[q] = zreg[q]; d1[q] = zreg[4 + q]; }
        *(f4*)&out[O4 + R * 32 + u * 8] = d0;
        *(f4*)&out[O4 + R * 32 + u * 8 + 4] = d1;
    }

    // points
    {
        f4 pk[6];
#pragma unroll
        for (int q = 0; q < 8; q++) {
            float z = zreg[q];
            float y0 = fmaf(z, dx, camx), y1 = fmaf(z, dy, camy), y2 = fmaf(z, dz, camz);
            float v0 = fmaf(y0, A[0], Bc[0]);
            float v1 = fmaf(y1, A[1], Bc[1]);
            float v2 = fmaf(y2, A[2], Bc[2]);
#pragma unroll
            for (int c = 0; c < 3; c++) {
                int ee = q * 3 + c;
                float vv = (c == 0) ? v0 : ((c == 1) ? v1 : v2);
                pk[ee >> 2][ee & 3] = vv;
            }
        }
        int pbase = O3 + R * 96 + u * 24;
#pragma unroll
        for (int s6 = 0; s6 < 6; s6++) *(f4*)&out[pbase + s6 * 4] = pk[s6];
    }

    // ---- sampler_transforms: broadcast T rows, coalesced per wave ----
    {
        f4 myrow = *(const f4*)&Tmat[(lane & 3) * 4];
        int base = O5 + rayBase * 512;
#pragma unroll
        for (int cc = 0; cc < 32; cc++) {
            int g = lane + 64 * cc;
            *(f4*)&out[base + g * 4] = myrow;
        }
    }
}

extern "C" void kernel_launch(void* const* d_in, const int* in_sizes, int n_in,
                              void* d_out, int out_size, void* d_ws, size_t ws_size,
                              hipStream_t stream) {
    (void)n_in; (void)out_size; (void)ws_size;
    const float* cam  = (const float*)d_in[0];
    const float* dirs = (const float*)d_in[1];
    const float* bbi  = (const float*)d_in[2];
    const float* loc  = (const float*)d_in[3];
    const float* scf  = (const float*)d_in[4];
    const float* sw   = (const float*)d_in[7];
    const float* bt   = (const float*)d_in[8];
    const float* trn  = (const float*)d_in[9];
    const float* cmn  = (const float*)d_in[10];
    const float* cmx  = (const float*)d_in[11];
    const float* cen  = (const float*)d_in[12];
    const float* W1   = (const float*)d_in[13];
    const float* b1   = (const float*)d_in[14];
    const float* W2   = (const float*)d_in[15];
    const float* b2   = (const float*)d_in[16];
    const float* W3   = (const float*)d_in[17];
    const float* b3   = (const float*)d_in[18];

    float* Tout = (float*)d_ws;
    int N = in_sizes[1] / 3;
    int V = in_sizes[7] / 24;

    hipLaunchKernelGGL(t_kernel, dim3(1), dim3(256), 0, stream, sw, bt, Tout, V);
    hipLaunchKernelGGL(main_kernel, dim3(N / 64), dim3(256), 0, stream,
                       cam, dirs, bbi, loc, scf, trn, cmn, cmx, cen,
                       W1, b1, W2, b2, W3, b3, Tout,
                       (float*)d_out, N);
}